// Round 4
// baseline (1717.783 us; speedup 1.0000x reference)
//
#include <hip/hip_runtime.h>
#include <math.h>

#define N1c 10000
#define N2c 10000
#define F_INc 256
#define Ec 480000
#define Pc 200000
#define HIDc 128
#define Hc 8
#define DHc 16
#define Lc 2
#define NPART 32
#define NPc 313   // ceil(10000/32)

using short8 = __attribute__((ext_vector_type(8))) short;
using float4v = __attribute__((ext_vector_type(4))) float;

__device__ __forceinline__ float gelu_f(float x) {
    const float k0 = 0.7978845608028654f;
    const float k1 = 0.044715f;
    float x3 = x * x * x;
    float t = tanhf(k0 * (x + k1 * x3));
    return 0.5f * x * (1.0f + t);
}

__device__ __forceinline__ float bf2f(unsigned short x) {
    union { unsigned int u; float f; } c;
    c.u = ((unsigned int)x) << 16;
    return c.f;
}
__device__ __forceinline__ unsigned short f2bf(float f) {
    union { float f; unsigned int u; } c;
    c.f = f;
    unsigned int u = c.u;
    unsigned int r = (u + 0x7FFFu + ((u >> 16) & 1u)) >> 16;
    return (unsigned short)r;
}

// ---------------- combined effective weights -> bf16, [n][k] layout ----------------
// Wqkvt[lt][col(0..383)][c(0..127)]; col<128: Wq; 128..255: Wk@arel*prior/4; 256..383: Wv@mrel
__global__ __launch_bounds__(128) void make_eff_kernel(
    const float* __restrict__ Wq, const float* __restrict__ bq,
    const float* __restrict__ Wk, const float* __restrict__ bk,
    const float* __restrict__ Wv, const float* __restrict__ bv,
    const float* __restrict__ arel, const float* __restrict__ mrel,
    const float* __restrict__ prior,
    short* __restrict__ Wqkvt, float* __restrict__ bqkv)
{
    int col = blockIdx.x * 128 + threadIdx.x;   // 0..383
    int c = blockIdx.y;                          // 0..127 (k)
    int lt = blockIdx.z;                         // 0..3
    short* Wout = Wqkvt + (size_t)lt * 384 * 128;
    float* bout = bqkv + lt * 384;
    if (col < 128) {
        Wout[col * 128 + c] = (short)f2bf(Wq[lt * 16384 + c * 128 + col]);
        if (c == 0) bout[col] = bq[lt * 128 + col];
        return;
    }
    int which = (col < 256) ? 0 : 1;
    int he = col - (which ? 256 : 128);
    int h = he >> 4, e = he & 15;
    const float* W = (which == 0 ? Wk : Wv) + lt * 16384;
    const float* b = (which == 0 ? bk : bv) + lt * 128;
    const float* R = (which == 0 ? arel : mrel) + lt * 2048;
    float sc = (which == 0) ? prior[lt * 8 + h] * 0.25f : 1.0f;
    float acc = 0.f;
    #pragma unroll
    for (int d = 0; d < 16; d++)
        acc += W[c * 128 + h * 16 + d] * R[(h * 16 + d) * 16 + e];
    Wout[col * 128 + c] = (short)f2bf(acc * sc);
    if (c == 0) {
        float bacc = 0.f;
        #pragma unroll
        for (int d = 0; d < 16; d++)
            bacc += b[h * 16 + d] * R[(h * 16 + d) * 16 + e];
        bout[col] = bacc * sc;
    }
}

// ---------------- transpose+bf16 Win1/Win2/Wa ----------------
__global__ __launch_bounds__(256) void wt_prep_kernel(
    const float* __restrict__ Win1, const float* __restrict__ Win2,
    const float* __restrict__ Wa,
    short* __restrict__ Wint1, short* __restrict__ Wint2, short* __restrict__ Wat)
{
    int y = blockIdx.y;
    int id = blockIdx.x * 256 + threadIdx.x;
    if (y < 2) {   // Win: [256][128] -> [128][256]
        if (id >= 128 * 256) return;
        int n = id >> 8, k = id & 255;
        const float* W = y ? Win2 : Win1;
        short* O = y ? Wint2 : Wint1;
        O[n * 256 + k] = (short)f2bf(W[k * 128 + n]);
    } else {       // Wa[lt]: [128][128] -> transposed
        if (id >= 128 * 128) return;
        int lt = y - 2;
        int n = id >> 7, k = id & 127;
        Wat[lt * 16384 + n * 128 + k] = (short)f2bf(Wa[lt * 16384 + k * 128 + n]);
    }
}

// ---------------- CSR build: partitioned (no global atomics, local writes) ----------------
__global__ __launch_bounds__(256) void count_part_kernel(
    const int* __restrict__ ei12, const int* __restrict__ ei21, const int* __restrict__ eidx,
    int* __restrict__ deg12, int* __restrict__ deg21, int* __restrict__ degm)
{
    int part = blockIdx.x, z = blockIdx.y, t = threadIdx.x;
    const int* dst; int* deg; int E;
    if (z == 0)      { dst = ei12 + Ec; deg = deg12; E = Ec; }
    else if (z == 1) { dst = ei21 + Ec; deg = deg21; E = Ec; }
    else             { dst = eidx;      deg = degm;  E = Pc; }
    int lo = part * NPc;
    __shared__ int cnt[NPc];
    for (int i = t; i < NPc; i += 256) cnt[i] = 0;
    __syncthreads();
    for (int e = t; e < E; e += 256) {
        int d = dst[e] - lo;
        if ((unsigned)d < (unsigned)NPc) atomicAdd(&cnt[d], 1);
    }
    __syncthreads();
    for (int i = t; i < NPc; i += 256) {
        int n = lo + i;
        if (n < 10000) deg[n] = cnt[i];
    }
}

__global__ __launch_bounds__(1024) void scan3_kernel(
    const int* __restrict__ deg12, int* __restrict__ rp12,
    const int* __restrict__ deg21, int* __restrict__ rp21,
    const int* __restrict__ degm,  int* __restrict__ rpm)
{
    const int n = 10000;
    const int* deg; int* rowptr;
    if (blockIdx.x == 0)      { deg = deg12; rowptr = rp12; }
    else if (blockIdx.x == 1) { deg = deg21; rowptr = rp21; }
    else                      { deg = degm;  rowptr = rpm; }
    __shared__ int sums[1024];
    int t = threadIdx.x;
    const int CH = (n + 1023) / 1024;
    int base = t * CH;
    int loc[16];
    int s = 0;
    for (int j = 0; j < CH; j++) {
        int v = (base + j < n) ? deg[base + j] : 0;
        loc[j] = s; s += v;
    }
    sums[t] = s;
    __syncthreads();
    for (int off = 1; off < 1024; off <<= 1) {
        int v = (t >= off) ? sums[t - off] : 0;
        __syncthreads();
        sums[t] += v;
        __syncthreads();
    }
    int excl = (t == 0) ? 0 : sums[t - 1];
    for (int j = 0; j < CH; j++)
        if (base + j < n) rowptr[base + j] = excl + loc[j];
    if (t == 1023) rowptr[n] = sums[1023];
}

__global__ __launch_bounds__(256) void scatter_part_kernel(
    const int* __restrict__ ei12, const int* __restrict__ ei21, const int* __restrict__ eidx,
    const int* __restrict__ rp12, const int* __restrict__ rp21, const int* __restrict__ rpm,
    int* __restrict__ es12, int* __restrict__ es21, int* __restrict__ ps)
{
    int part = blockIdx.x, z = blockIdx.y, t = threadIdx.x;
    const int* dst; const int* src; const int* rp; int* out; int E;
    if (z == 0)      { dst = ei12 + Ec; src = ei12; rp = rp12; out = es12; E = Ec; }
    else if (z == 1) { dst = ei21 + Ec; src = ei21; rp = rp21; out = es21; E = Ec; }
    else             { dst = eidx;      src = nullptr; rp = rpm; out = ps; E = Pc; }
    int lo = part * NPc;
    __shared__ int fill[NPc];
    for (int i = t; i < NPc; i += 256) fill[i] = 0;
    __syncthreads();
    for (int e = t; e < E; e += 256) {
        int dv = dst[e];
        int d = dv - lo;
        if ((unsigned)d < (unsigned)NPc) {
            int pos = rp[dv] + atomicAdd(&fill[d], 1);
            out[pos] = (z == 2) ? e : src[e];
        }
    }
}

// ---------------- bf16 MFMA GEMM: 64x64 tile, 4 waves, 16x16x32 ----------------
// A fp32 [M][ldA] -> bf16 in staging (optional gelu). Wt bf16 [N][K]. fp32 accum.
// PACKQKV: col<128 -> fp32 C; col>=128 -> bf16 KV[row][256]
template<int A_GELU, int OUT_RELU, int SKIP, int PACKQKV>
__global__ __launch_bounds__(256) void gemm_mfma(
    const float* __restrict__ A0, const float* __restrict__ A1, int ldA,
    const short* __restrict__ Wt0, const short* __restrict__ Wt1,
    const float* __restrict__ b0, const float* __restrict__ b1,
    float* __restrict__ C0, float* __restrict__ C1, int ldC,
    unsigned short* __restrict__ KV0, unsigned short* __restrict__ KV1,
    int M, int K,
    const float* __restrict__ sk0, const float* __restrict__ sk1,
    const float* __restrict__ H0, const float* __restrict__ H1, int ldH)
{
    int z = blockIdx.z;
    const float* A = z ? A1 : A0;
    const short* Wt = z ? Wt1 : Wt0;
    const float* bias = z ? b1 : b0;
    float* C = z ? C1 : C0;
    unsigned short* KVo = z ? KV1 : KV0;
    const float* skipv = z ? sk1 : sk0;
    const float* Hold = z ? H1 : H0;

    __shared__ short Alds[64 * 40];   // stride 40 bf16 = 80B: 2-way bank alias (free), 16B-aligned
    __shared__ short Blds[64 * 40];

    int tid = threadIdx.x;
    int w = tid >> 6;          // wave 0..3 -> n-strip
    int l = tid & 63;
    int mBase = blockIdx.x * 64;
    int nBase = blockIdx.y * 64;

    int srow = tid >> 2;       // staging row 0..63
    int koct = tid & 3;        // k-octet 0..3

    float4v acc[4];
    #pragma unroll
    for (int i = 0; i < 4; i++) acc[i] = (float4v){0.f, 0.f, 0.f, 0.f};

    int arow = mBase + srow;
    const float* Aptr = A + (size_t)arow * ldA + koct * 8;
    const short* Wptr = Wt + (size_t)(nBase + srow) * K + koct * 8;

    int fl = l & 15;           // frag row/col within 16
    int fo = (l >> 4) * 8;     // frag k-octet offset

    for (int k0 = 0; k0 < K; k0 += 32) {
        // stage A (fp32 -> bf16, optional gelu)
        float av[8];
        if (arow < M) {
            const float4* p = (const float4*)(Aptr + k0);
            float4 f0 = p[0], f1 = p[1];
            av[0] = f0.x; av[1] = f0.y; av[2] = f0.z; av[3] = f0.w;
            av[4] = f1.x; av[5] = f1.y; av[6] = f1.z; av[7] = f1.w;
        } else {
            #pragma unroll
            for (int i = 0; i < 8; i++) av[i] = 0.f;
        }
        if (A_GELU) {
            #pragma unroll
            for (int i = 0; i < 8; i++) av[i] = gelu_f(av[i]);
        }
        unsigned int pk[4];
        #pragma unroll
        for (int i = 0; i < 4; i++)
            pk[i] = (unsigned int)f2bf(av[2 * i]) | ((unsigned int)f2bf(av[2 * i + 1]) << 16);
        *(uint4*)&Alds[srow * 40 + koct * 8] = make_uint4(pk[0], pk[1], pk[2], pk[3]);
        // stage B (already bf16, [n][k])
        *(uint4*)&Blds[srow * 40 + koct * 8] = *(const uint4*)(Wptr + k0);
        __syncthreads();

        short8 bfr = *(const short8*)&Blds[(w * 16 + fl) * 40 + fo];
        #pragma unroll
        for (int msub = 0; msub < 4; msub++) {
            short8 afr = *(const short8*)&Alds[(msub * 16 + fl) * 40 + fo];
            acc[msub] = __builtin_amdgcn_mfma_f32_16x16x32_bf16(afr, bfr, acc[msub], 0, 0, 0);
        }
        __syncthreads();
    }

    float sig = 0.f;
    if (SKIP) sig = 1.f / (1.f + __expf(-skipv[0]));
    int col = nBase + w * 16 + fl;
    float bcol = bias[col];
    int rbase = mBase + ((l >> 4) * 4);
    #pragma unroll
    for (int msub = 0; msub < 4; msub++) {
        #pragma unroll
        for (int r = 0; r < 4; r++) {
            int row = rbase + msub * 16 + r;
            if (row >= M) continue;
            float v = acc[msub][r] + bcol;
            if (OUT_RELU) v = fmaxf(v, 0.f);
            if (SKIP) v = sig * v + (1.f - sig) * Hold[(size_t)row * ldH + col];
            if (PACKQKV) {
                if (col < 128) C[(size_t)row * ldC + col] = v;
                else KVo[(size_t)row * 256 + (col - 128)] = f2bf(v);
            } else {
                C[(size_t)row * ldC + col] = v;
            }
        }
    }
}

// ---------------- merged attend: 2 nodes/block, 32 lanes/node, bf16 KV ----------------
__device__ __forceinline__ void upd4(float& m, float& s, float4& a,
                                     float p, float4 v) {
    float nm = fmaxf(m, p);
    float al = __expf(m - nm);
    float pe = __expf(p - nm);
    s = s * al + pe;
    a.x = a.x * al + pe * v.x;
    a.y = a.y * al + pe * v.y;
    a.z = a.z * al + pe * v.z;
    a.w = a.w * al + pe * v.w;
    m = nm;
}

__device__ __forceinline__ float4 bfv4(ushort4 u) {
    return make_float4(bf2f(u.x), bf2f(u.y), bf2f(u.z), bf2f(u.w));
}

__global__ __launch_bounds__(64) void attend2_kernel(
    const float* __restrict__ Q1, const unsigned short* __restrict__ KV1,
    const float* __restrict__ Q2, const unsigned short* __restrict__ KV2,
    const int* __restrict__ rp12, const int* __restrict__ es12,
    const int* __restrict__ rp21, const int* __restrict__ es21,
    float* __restrict__ agg1, float* __restrict__ agg2)
{
    int b = blockIdx.x;
    int half = threadIdx.x >> 5;
    int l = threadIdx.x & 31;
    const float* Q; const unsigned short* KV; const int* rp; const int* es; float* out; int n;
    if (b < N2c / 2) { n = 2 * b + half;              Q = Q2; KV = KV1; rp = rp12; es = es12; out = agg2; }
    else             { n = 2 * (b - N2c / 2) + half;  Q = Q1; KV = KV2; rp = rp21; es = es21; out = agg1; }

    float4 q = *(const float4*)(Q + (size_t)n * 128 + 4 * l);
    int beg = rp[n], end = rp[n + 1];
    float m0 = -INFINITY, m1 = -INFINITY, m2 = -INFINITY, m3 = -INFINITY;
    float s0 = 0.f, s1 = 0.f, s2 = 0.f, s3 = 0.f;
    float4 a0 = {0,0,0,0}, a1 = {0,0,0,0}, a2 = {0,0,0,0}, a3 = {0,0,0,0};
    int i = beg;
    for (; i + 4 <= end; i += 4) {
        int e0 = es[i], e1 = es[i+1], e2 = es[i+2], e3 = es[i+3];
        const unsigned short* r0 = KV + (size_t)e0 * 256 + 4 * l;
        const unsigned short* r1 = KV + (size_t)e1 * 256 + 4 * l;
        const unsigned short* r2 = KV + (size_t)e2 * 256 + 4 * l;
        const unsigned short* r3 = KV + (size_t)e3 * 256 + 4 * l;
        float4 k0 = bfv4(*(const ushort4*)r0), v0 = bfv4(*(const ushort4*)(r0 + 128));
        float4 k1 = bfv4(*(const ushort4*)r1), v1 = bfv4(*(const ushort4*)(r1 + 128));
        float4 k2 = bfv4(*(const ushort4*)r2), v2 = bfv4(*(const ushort4*)(r2 + 128));
        float4 k3 = bfv4(*(const ushort4*)r3), v3 = bfv4(*(const ushort4*)(r3 + 128));
        float p0 = q.x*k0.x + q.y*k0.y + q.z*k0.z + q.w*k0.w;
        float p1 = q.x*k1.x + q.y*k1.y + q.z*k1.z + q.w*k1.w;
        float p2 = q.x*k2.x + q.y*k2.y + q.z*k2.z + q.w*k2.w;
        float p3 = q.x*k3.x + q.y*k3.y + q.z*k3.z + q.w*k3.w;
        p0 += __shfl_xor(p0, 1, 4); p1 += __shfl_xor(p1, 1, 4);
        p2 += __shfl_xor(p2, 1, 4); p3 += __shfl_xor(p3, 1, 4);
        p0 += __shfl_xor(p0, 2, 4); p1 += __shfl_xor(p1, 2, 4);
        p2 += __shfl_xor(p2, 2, 4); p3 += __shfl_xor(p3, 2, 4);
        upd4(m0, s0, a0, p0, v0);
        upd4(m1, s1, a1, p1, v1);
        upd4(m2, s2, a2, p2, v2);
        upd4(m3, s3, a3, p3, v3);
    }
    for (; i < end; i++) {
        int e0 = es[i];
        const unsigned short* r0 = KV + (size_t)e0 * 256 + 4 * l;
        float4 k0 = bfv4(*(const ushort4*)r0), v0 = bfv4(*(const ushort4*)(r0 + 128));
        float p0 = q.x*k0.x + q.y*k0.y + q.z*k0.z + q.w*k0.w;
        p0 += __shfl_xor(p0, 1, 4);
        p0 += __shfl_xor(p0, 2, 4);
        upd4(m0, s0, a0, p0, v0);
    }
    float M = fmaxf(fmaxf(m0, m1), fmaxf(m2, m3));
    float4 o = {0,0,0,0};
    if (M != -INFINITY) {
        float w0 = __expf(m0 - M), w1 = __expf(m1 - M);
        float w2 = __expf(m2 - M), w3 = __expf(m3 - M);
        float ssum = s0 * w0 + s1 * w1 + s2 * w2 + s3 * w3;
        float inv = 1.f / (ssum + 1e-16f);
        o.x = (a0.x*w0 + a1.x*w1 + a2.x*w2 + a3.x*w3) * inv;
        o.y = (a0.y*w0 + a1.y*w1 + a2.y*w2 + a3.y*w3) * inv;
        o.z = (a0.z*w0 + a1.z*w1 + a2.z*w2 + a3.z*w3) * inv;
        o.w = (a0.w*w0 + a1.w*w1 + a2.w*w2 + a3.w*w3) * inv;
    }
    *(float4*)(out + (size_t)n * 128 + 4 * l) = o;
}

// ---------------- pred: one block per m-node, Em row in regs ----------------
__global__ __launch_bounds__(64) void pred_kernel(
    const float* __restrict__ Em, const float* __restrict__ Ed,
    const int* __restrict__ eidx,
    const int* __restrict__ rpm, const int* __restrict__ porder,
    float* __restrict__ out)
{
    int m = blockIdx.x;
    int lane = threadIdx.x;
    int beg = rpm[m], end = rpm[m + 1];
    if (beg == end) return;
    float4 a = *(const float4*)(Em + (size_t)m * 256 + 4 * lane);
    int i = beg;
    for (; i + 2 <= end; i += 2) {
        int p0 = porder[i], p1 = porder[i + 1];
        int d0 = eidx[Pc + p0], d1 = eidx[Pc + p1];
        float4 b0 = *(const float4*)(Ed + (size_t)d0 * 256 + 4 * lane);
        float4 b1 = *(const float4*)(Ed + (size_t)d1 * 256 + 4 * lane);
        float s0 = a.x*b0.x + a.y*b0.y + a.z*b0.z + a.w*b0.w;
        float s1 = a.x*b1.x + a.y*b1.y + a.z*b1.z + a.w*b1.w;
        #pragma unroll
        for (int o = 1; o < 64; o <<= 1) { s0 += __shfl_xor(s0, o); s1 += __shfl_xor(s1, o); }
        if (lane == 0) { out[p0] = s0; out[p1] = s1; }
    }
    if (i < end) {
        int p0 = porder[i];
        int d0 = eidx[Pc + p0];
        float4 b0 = *(const float4*)(Ed + (size_t)d0 * 256 + 4 * lane);
        float s0 = a.x*b0.x + a.y*b0.y + a.z*b0.z + a.w*b0.w;
        #pragma unroll
        for (int o = 1; o < 64; o <<= 1) s0 += __shfl_xor(s0, o);
        if (lane == 0) out[p0] = s0;
    }
}

extern "C" void kernel_launch(void* const* d_in, const int* in_sizes, int n_in,
                              void* d_out, int out_size, void* d_ws, size_t ws_size,
                              hipStream_t stream)
{
    const float* x1   = (const float*)d_in[0];
    const float* x2   = (const float*)d_in[1];
    const int*   ei12 = (const int*)d_in[2];
    const int*   ei21 = (const int*)d_in[3];
    const int*   eidx = (const int*)d_in[4];
    const float* Win1 = (const float*)d_in[5];
    const float* bin1 = (const float*)d_in[6];
    const float* Win2 = (const float*)d_in[7];
    const float* bin2 = (const float*)d_in[8];
    const float* Wk   = (const float*)d_in[9];
    const float* bk   = (const float*)d_in[10];
    const float* Wq   = (const float*)d_in[11];
    const float* bq   = (const float*)d_in[12];
    const float* Wv   = (const float*)d_in[13];
    const float* bv   = (const float*)d_in[14];
    const float* Wa   = (const float*)d_in[15];
    const float* ba   = (const float*)d_in[16];
    const float* skip = (const float*)d_in[17];
    const float* arel = (const float*)d_in[18];
    const float* mrel = (const float*)d_in[19];
    const float* prior= (const float*)d_in[20];

    char* ws = (char*)d_ws;
    size_t off = 0;
    auto allocB = [&](size_t bytes) { void* p = ws + off; off += (bytes + 15) & ~15ull; return p; };
    auto allocF = [&](size_t n) { return (float*)allocB(n * 4); };
    auto allocI = [&](size_t n) { return (int*)allocB(n * 4); };
    auto allocS = [&](size_t n) { return (short*)allocB(n * 2); };

    float* h1    = allocF((size_t)N1c * 128);
    float* h2    = allocF((size_t)N2c * 128);
    float* Q1    = allocF((size_t)N1c * 128);
    float* Q2    = allocF((size_t)N2c * 128);
    float* agg1  = allocF((size_t)N1c * 128);
    float* agg2  = allocF((size_t)N2c * 128);
    float* Em    = allocF((size_t)N1c * 256);
    float* Ed    = allocF((size_t)N2c * 256);
    float* bqkv  = allocF(4 * 384);
    short* Wqkvt = allocS(4 * 384 * 128);
    short* Wint1 = allocS(128 * 256);
    short* Wint2 = allocS(128 * 256);
    short* Wat   = allocS(4 * 128 * 128);
    unsigned short* KV1 = (unsigned short*)allocS((size_t)N1c * 256);
    unsigned short* KV2 = (unsigned short*)allocS((size_t)N2c * 256);
    int* deg12 = allocI(N2c);
    int* deg21 = allocI(N1c);
    int* degm  = allocI(N1c);
    int* rp12  = allocI(N2c + 1);
    int* rp21  = allocI(N1c + 1);
    int* rpm   = allocI(N1c + 1);
    int* es12  = allocI(Ec);
    int* es21  = allocI(Ec);
    int* ps    = allocI(Pc);

    make_eff_kernel<<<dim3(3, 128, 4), 128, 0, stream>>>(
        Wq, bq, Wk, bk, Wv, bv, arel, mrel, prior, Wqkvt, bqkv);
    wt_prep_kernel<<<dim3(128, 6), 256, 0, stream>>>(Win1, Win2, Wa, Wint1, Wint2, Wat);

    count_part_kernel<<<dim3(NPART, 3), 256, 0, stream>>>(ei12, ei21, eidx, deg12, deg21, degm);
    scan3_kernel<<<3, 1024, 0, stream>>>(deg12, rp12, deg21, rp21, degm, rpm);
    scatter_part_kernel<<<dim3(NPART, 3), 256, 0, stream>>>(ei12, ei21, eidx, rp12, rp21, rpm,
                                                            es12, es21, ps);

    const int MB = (N1c + 63) / 64;   // 157
    // input projections (relu), K=256
    gemm_mfma<0, 1, 0, 0><<<dim3(MB, 2, 2), 256, 0, stream>>>(
        x1, x2, F_INc, Wint1, Wint2, bin1, bin2, h1, h2, 128,
        nullptr, nullptr,
        N1c, F_INc, nullptr, nullptr, nullptr, nullptr, 0);

    for (int l = 0; l < Lc; l++) {
        const float* A1 = (l == 0) ? h1 : Em;  int ld1 = (l == 0) ? 128 : 256;
        const float* A2 = (l == 0) ? h2 : Ed;
        int lt0 = l * 2 + 0, lt1 = l * 2 + 1;
        // fused QKV projections: Q fp32, KV bf16 packed
        gemm_mfma<0, 0, 0, 1><<<dim3(MB, 6, 2), 256, 0, stream>>>(
            A1, A2, ld1,
            Wqkvt + (size_t)lt0 * 49152, Wqkvt + (size_t)lt1 * 49152,
            bqkv + lt0 * 384, bqkv + lt1 * 384,
            Q1, Q2, 128,
            KV1, KV2,
            N1c, 128,
            nullptr, nullptr, nullptr, nullptr, 0);
        // both attends in one dispatch
        attend2_kernel<<<(N1c + N2c) / 2, 64, 0, stream>>>(
            Q1, KV1, Q2, KV2, rp12, es12, rp21, es21, agg1, agg2);
        // output GEMMs (gelu on A in staging, skip blend) into concat buffers
        gemm_mfma<1, 0, 1, 0><<<dim3(MB, 2, 2), 256, 0, stream>>>(
            agg1, agg2, 128,
            Wat + (size_t)lt0 * 16384, Wat + (size_t)lt1 * 16384,
            ba + lt0 * 128, ba + lt1 * 128,
            Em + l * 128, Ed + l * 128, 256,
            nullptr, nullptr,
            N1c, 128,
            skip + lt0, skip + lt1,
            A1, A2, ld1);
    }

    pred_kernel<<<N1c, 64, 0, stream>>>(Em, Ed, eidx, rpm, ps, (float*)d_out);
}

// Round 5
// 365.657 us; speedup vs baseline: 4.6978x; 4.6978x over previous
//
#include <hip/hip_runtime.h>
#include <math.h>

#define N1c 10000
#define N2c 10000
#define F_INc 256
#define Ec 480000
#define Pc 200000
#define HIDc 128
#define Hc 8
#define DHc 16
#define Lc 2
#define NPART 32
#define NPc 313   // ceil(10000/32)
#define NBLK 256  // chunks per edge structure

using short8 = __attribute__((ext_vector_type(8))) short;
using float4v = __attribute__((ext_vector_type(4))) float;

__device__ __forceinline__ float gelu_f(float x) {
    const float k0 = 0.7978845608028654f;
    const float k1 = 0.044715f;
    float x3 = x * x * x;
    float t = tanhf(k0 * (x + k1 * x3));
    return 0.5f * x * (1.0f + t);
}

__device__ __forceinline__ float bf2f(unsigned short x) {
    union { unsigned int u; float f; } c;
    c.u = ((unsigned int)x) << 16;
    return c.f;
}
__device__ __forceinline__ unsigned short f2bf(float f) {
    union { float f; unsigned int u; } c;
    c.f = f;
    unsigned int u = c.u;
    unsigned int r = (u + 0x7FFFu + ((u >> 16) & 1u)) >> 16;
    return (unsigned short)r;
}

// ---------------- combined effective weights -> bf16, [n][k] layout ----------------
__global__ __launch_bounds__(128) void make_eff_kernel(
    const float* __restrict__ Wq, const float* __restrict__ bq,
    const float* __restrict__ Wk, const float* __restrict__ bk,
    const float* __restrict__ Wv, const float* __restrict__ bv,
    const float* __restrict__ arel, const float* __restrict__ mrel,
    const float* __restrict__ prior,
    short* __restrict__ Wqkvt, float* __restrict__ bqkv)
{
    int col = blockIdx.x * 128 + threadIdx.x;   // 0..383
    int c = blockIdx.y;                          // 0..127 (k)
    int lt = blockIdx.z;                         // 0..3
    short* Wout = Wqkvt + (size_t)lt * 384 * 128;
    float* bout = bqkv + lt * 384;
    if (col < 128) {
        Wout[col * 128 + c] = (short)f2bf(Wq[lt * 16384 + c * 128 + col]);
        if (c == 0) bout[col] = bq[lt * 128 + col];
        return;
    }
    int which = (col < 256) ? 0 : 1;
    int he = col - (which ? 256 : 128);
    int h = he >> 4, e = he & 15;
    const float* W = (which == 0 ? Wk : Wv) + lt * 16384;
    const float* b = (which == 0 ? bk : bv) + lt * 128;
    const float* R = (which == 0 ? arel : mrel) + lt * 2048;
    float sc = (which == 0) ? prior[lt * 8 + h] * 0.25f : 1.0f;
    float acc = 0.f;
    #pragma unroll
    for (int d = 0; d < 16; d++)
        acc += W[c * 128 + h * 16 + d] * R[(h * 16 + d) * 16 + e];
    Wout[col * 128 + c] = (short)f2bf(acc * sc);
    if (c == 0) {
        float bacc = 0.f;
        #pragma unroll
        for (int d = 0; d < 16; d++)
            bacc += b[h * 16 + d] * R[(h * 16 + d) * 16 + e];
        bout[col] = bacc * sc;
    }
}

// ---------------- transpose+bf16 Win1/Win2/Wa ----------------
__global__ __launch_bounds__(256) void wt_prep_kernel(
    const float* __restrict__ Win1, const float* __restrict__ Win2,
    const float* __restrict__ Wa,
    short* __restrict__ Wint1, short* __restrict__ Wint2, short* __restrict__ Wat)
{
    int y = blockIdx.y;
    int id = blockIdx.x * 256 + threadIdx.x;
    if (y < 2) {   // Win: [256][128] -> [128][256]
        if (id >= 128 * 256) return;
        int n = id >> 8, k = id & 255;
        const float* W = y ? Win2 : Win1;
        short* O = y ? Wint2 : Wint1;
        O[n * 256 + k] = (short)f2bf(W[k * 128 + n]);
    } else {       // Wa[lt]: [128][128] -> transposed
        if (id >= 128 * 128) return;
        int lt = y - 2;
        int n = id >> 7, k = id & 127;
        Wat[lt * 16384 + n * 128 + k] = (short)f2bf(Wa[lt * 16384 + k * 128 + n]);
    }
}

// ---------------- CSR build: two-level binned sort ----------------
// z=0: graph ei12 (key=dst in N2); z=1: ei21; z=2: pred pairs (key=m)
// Level 1: NBLK blocks per structure, contiguous chunks, 32-bin LDS count.
__global__ __launch_bounds__(256) void count_bins_kernel(
    const int* __restrict__ ei12, const int* __restrict__ ei21, const int* __restrict__ eidx,
    int* __restrict__ cntmat)   // [z][part][blk]
{
    int blk = blockIdx.x, z = blockIdx.y, t = threadIdx.x;
    const int* key; int E;
    if (z == 0)      { key = ei12 + Ec; E = Ec; }
    else if (z == 1) { key = ei21 + Ec; E = Ec; }
    else             { key = eidx;      E = Pc; }
    int chunk = (E + NBLK - 1) / NBLK;
    int start = blk * chunk;
    int stop = min(start + chunk, E);
    __shared__ int cnt[NPART];
    if (t < NPART) cnt[t] = 0;
    __syncthreads();
    for (int e = start + t; e < stop; e += 256)
        atomicAdd(&cnt[key[e] / NPc], 1);
    __syncthreads();
    if (t < NPART) cntmat[z * (NPART * NBLK) + t * NBLK + blk] = cnt[t];
}

// exclusive scan of the 32x256 matrix (part-major), one block per z
__global__ __launch_bounds__(256) void scan_bins_kernel(
    const int* __restrict__ cntmat, int* __restrict__ offmat)
{
    int z = blockIdx.x, t = threadIdx.x;
    const int* c = cntmat + z * (NPART * NBLK);
    int* o = offmat + z * (NPART * NBLK);
    int loc[32];
    int base = t * 32;
    int s = 0;
    #pragma unroll
    for (int j = 0; j < 32; j++) { loc[j] = s; s += c[base + j]; }
    __shared__ int ws[256];
    ws[t] = s;
    __syncthreads();
    for (int off = 1; off < 256; off <<= 1) {
        int v = (t >= off) ? ws[t - off] : 0;
        __syncthreads();
        ws[t] += v;
        __syncthreads();
    }
    int excl = t ? ws[t - 1] : 0;
    #pragma unroll
    for (int j = 0; j < 32; j++) o[base + j] = excl + loc[j];
}

// Level-1 write: (key,payload) pairs into partition-major staging, ~470B runs
__global__ __launch_bounds__(256) void binwrite_kernel(
    const int* __restrict__ ei12, const int* __restrict__ ei21, const int* __restrict__ eidx,
    const int* __restrict__ offmat,
    int2* __restrict__ stg12, int2* __restrict__ stg21, int2* __restrict__ stgm)
{
    int blk = blockIdx.x, z = blockIdx.y, t = threadIdx.x;
    const int* key; const int* pay; int E; int2* stg;
    if (z == 0)      { key = ei12 + Ec; pay = ei12; E = Ec; stg = stg12; }
    else if (z == 1) { key = ei21 + Ec; pay = ei21; E = Ec; stg = stg21; }
    else             { key = eidx;      pay = nullptr; E = Pc; stg = stgm; }
    int chunk = (E + NBLK - 1) / NBLK;
    int start = blk * chunk;
    int stop = min(start + chunk, E);
    const int* om = offmat + z * (NPART * NBLK);
    __shared__ int fill[NPART];
    __shared__ int obase[NPART];
    if (t < NPART) { fill[t] = 0; obase[t] = om[t * NBLK + blk]; }
    __syncthreads();
    for (int e = start + t; e < stop; e += 256) {
        int k = key[e];
        int p = k / NPc;
        int r = atomicAdd(&fill[p], 1);
        stg[obase[p] + r] = make_int2(k, (z == 2) ? e : pay[e]);
    }
}

// Level 2: one block per partition: LDS hist+scan -> rowptr + local scatter
__global__ __launch_bounds__(256) void build_csr_kernel(
    const int* __restrict__ offmat,
    const int2* __restrict__ stg12, const int2* __restrict__ stg21, const int2* __restrict__ stgm,
    int* __restrict__ rp12, int* __restrict__ rp21, int* __restrict__ rpm,
    int* __restrict__ es12, int* __restrict__ es21, int* __restrict__ ps)
{
    int p = blockIdx.x, z = blockIdx.y, t = threadIdx.x;
    const int2* stg; int* rowptr; int* out; int E;
    if (z == 0)      { stg = stg12; rowptr = rp12; out = es12; E = Ec; }
    else if (z == 1) { stg = stg21; rowptr = rp21; out = es21; E = Ec; }
    else             { stg = stgm;  rowptr = rpm;  out = ps;   E = Pc; }
    const int* om = offmat + z * (NPART * NBLK);
    int base = om[p * NBLK];
    int next = (p == NPART - 1) ? E : om[(p + 1) * NBLK];
    int cntP = next - base;
    int lo = p * NPc;
    int hi = min(lo + NPc, 10000);

    __shared__ int hist[512];
    __shared__ int fill[NPc];
    hist[t] = 0; hist[t + 256] = 0;
    __syncthreads();
    for (int i = t; i < cntP; i += 256)
        atomicAdd(&hist[stg[base + i].x - lo], 1);
    __syncthreads();
    // inclusive Hillis-Steele over 512
    for (int off = 1; off < 512; off <<= 1) {
        int i0 = t, i1 = t + 256;
        int v0 = (i0 >= off) ? hist[i0 - off] : 0;
        int v1 = (i1 >= off) ? hist[i1 - off] : 0;
        __syncthreads();
        hist[i0] += v0; hist[i1] += v1;
        __syncthreads();
    }
    // exclusive offsets -> fill counters + rowptr
    for (int i = t; i < NPc; i += 256) {
        int excl = i ? hist[i - 1] : 0;
        fill[i] = excl;
        if (lo + i < hi) rowptr[lo + i] = base + excl;
    }
    if (p == NPART - 1 && t == 0) rowptr[10000] = E;
    __syncthreads();
    // scatter within contiguous partition window
    for (int i = t; i < cntP; i += 256) {
        int2 pr = stg[base + i];
        int r = atomicAdd(&fill[pr.x - lo], 1);
        out[base + r] = pr.y;
    }
}

// ---------------- bf16 MFMA GEMM: 64x64 tile, 4 waves, 16x16x32 ----------------
template<int A_GELU, int OUT_RELU, int SKIP, int PACKQKV>
__global__ __launch_bounds__(256) void gemm_mfma(
    const float* __restrict__ A0, const float* __restrict__ A1, int ldA,
    const short* __restrict__ Wt0, const short* __restrict__ Wt1,
    const float* __restrict__ b0, const float* __restrict__ b1,
    float* __restrict__ C0, float* __restrict__ C1, int ldC,
    unsigned short* __restrict__ KV0, unsigned short* __restrict__ KV1,
    int M, int K,
    const float* __restrict__ sk0, const float* __restrict__ sk1,
    const float* __restrict__ H0, const float* __restrict__ H1, int ldH)
{
    int z = blockIdx.z;
    const float* A = z ? A1 : A0;
    const short* Wt = z ? Wt1 : Wt0;
    const float* bias = z ? b1 : b0;
    float* C = z ? C1 : C0;
    unsigned short* KVo = z ? KV1 : KV0;
    const float* skipv = z ? sk1 : sk0;
    const float* Hold = z ? H1 : H0;

    __shared__ short Alds[64 * 40];
    __shared__ short Blds[64 * 40];

    int tid = threadIdx.x;
    int w = tid >> 6;
    int l = tid & 63;
    int mBase = blockIdx.x * 64;
    int nBase = blockIdx.y * 64;

    int srow = tid >> 2;
    int koct = tid & 3;

    float4v acc[4];
    #pragma unroll
    for (int i = 0; i < 4; i++) acc[i] = (float4v){0.f, 0.f, 0.f, 0.f};

    int arow = mBase + srow;
    const float* Aptr = A + (size_t)arow * ldA + koct * 8;
    const short* Wptr = Wt + (size_t)(nBase + srow) * K + koct * 8;

    int fl = l & 15;
    int fo = (l >> 4) * 8;

    for (int k0 = 0; k0 < K; k0 += 32) {
        float av[8];
        if (arow < M) {
            const float4* p = (const float4*)(Aptr + k0);
            float4 f0 = p[0], f1 = p[1];
            av[0] = f0.x; av[1] = f0.y; av[2] = f0.z; av[3] = f0.w;
            av[4] = f1.x; av[5] = f1.y; av[6] = f1.z; av[7] = f1.w;
        } else {
            #pragma unroll
            for (int i = 0; i < 8; i++) av[i] = 0.f;
        }
        if (A_GELU) {
            #pragma unroll
            for (int i = 0; i < 8; i++) av[i] = gelu_f(av[i]);
        }
        unsigned int pk[4];
        #pragma unroll
        for (int i = 0; i < 4; i++)
            pk[i] = (unsigned int)f2bf(av[2 * i]) | ((unsigned int)f2bf(av[2 * i + 1]) << 16);
        *(uint4*)&Alds[srow * 40 + koct * 8] = make_uint4(pk[0], pk[1], pk[2], pk[3]);
        *(uint4*)&Blds[srow * 40 + koct * 8] = *(const uint4*)(Wptr + k0);
        __syncthreads();

        short8 bfr = *(const short8*)&Blds[(w * 16 + fl) * 40 + fo];
        #pragma unroll
        for (int msub = 0; msub < 4; msub++) {
            short8 afr = *(const short8*)&Alds[(msub * 16 + fl) * 40 + fo];
            acc[msub] = __builtin_amdgcn_mfma_f32_16x16x32_bf16(afr, bfr, acc[msub], 0, 0, 0);
        }
        __syncthreads();
    }

    float sig = 0.f;
    if (SKIP) sig = 1.f / (1.f + __expf(-skipv[0]));
    int col = nBase + w * 16 + fl;
    float bcol = bias[col];
    int rbase = mBase + ((l >> 4) * 4);
    #pragma unroll
    for (int msub = 0; msub < 4; msub++) {
        #pragma unroll
        for (int r = 0; r < 4; r++) {
            int row = rbase + msub * 16 + r;
            if (row >= M) continue;
            float v = acc[msub][r] + bcol;
            if (OUT_RELU) v = fmaxf(v, 0.f);
            if (SKIP) v = sig * v + (1.f - sig) * Hold[(size_t)row * ldH + col];
            if (PACKQKV) {
                if (col < 128) C[(size_t)row * ldC + col] = v;
                else KVo[(size_t)row * 256 + (col - 128)] = f2bf(v);
            } else {
                C[(size_t)row * ldC + col] = v;
            }
        }
    }
}

// ---------------- merged attend: 2 nodes/block, 32 lanes/node, bf16 KV ----------------
__device__ __forceinline__ void upd4(float& m, float& s, float4& a,
                                     float p, float4 v) {
    float nm = fmaxf(m, p);
    float al = __expf(m - nm);
    float pe = __expf(p - nm);
    s = s * al + pe;
    a.x = a.x * al + pe * v.x;
    a.y = a.y * al + pe * v.y;
    a.z = a.z * al + pe * v.z;
    a.w = a.w * al + pe * v.w;
    m = nm;
}

__device__ __forceinline__ float4 bfv4(ushort4 u) {
    return make_float4(bf2f(u.x), bf2f(u.y), bf2f(u.z), bf2f(u.w));
}

__global__ __launch_bounds__(64) void attend2_kernel(
    const float* __restrict__ Q1, const unsigned short* __restrict__ KV1,
    const float* __restrict__ Q2, const unsigned short* __restrict__ KV2,
    const int* __restrict__ rp12, const int* __restrict__ es12,
    const int* __restrict__ rp21, const int* __restrict__ es21,
    float* __restrict__ agg1, float* __restrict__ agg2)
{
    int b = blockIdx.x;
    int half = threadIdx.x >> 5;
    int l = threadIdx.x & 31;
    const float* Q; const unsigned short* KV; const int* rp; const int* es; float* out; int n;
    if (b < N2c / 2) { n = 2 * b + half;              Q = Q2; KV = KV1; rp = rp12; es = es12; out = agg2; }
    else             { n = 2 * (b - N2c / 2) + half;  Q = Q1; KV = KV2; rp = rp21; es = es21; out = agg1; }

    float4 q = *(const float4*)(Q + (size_t)n * 128 + 4 * l);
    int beg = rp[n], end = rp[n + 1];
    float m0 = -INFINITY, m1 = -INFINITY, m2 = -INFINITY, m3 = -INFINITY;
    float s0 = 0.f, s1 = 0.f, s2 = 0.f, s3 = 0.f;
    float4 a0 = {0,0,0,0}, a1 = {0,0,0,0}, a2 = {0,0,0,0}, a3 = {0,0,0,0};
    int i = beg;
    for (; i + 4 <= end; i += 4) {
        int e0 = es[i], e1 = es[i+1], e2 = es[i+2], e3 = es[i+3];
        const unsigned short* r0 = KV + (size_t)e0 * 256 + 4 * l;
        const unsigned short* r1 = KV + (size_t)e1 * 256 + 4 * l;
        const unsigned short* r2 = KV + (size_t)e2 * 256 + 4 * l;
        const unsigned short* r3 = KV + (size_t)e3 * 256 + 4 * l;
        float4 k0 = bfv4(*(const ushort4*)r0), v0 = bfv4(*(const ushort4*)(r0 + 128));
        float4 k1 = bfv4(*(const ushort4*)r1), v1 = bfv4(*(const ushort4*)(r1 + 128));
        float4 k2 = bfv4(*(const ushort4*)r2), v2 = bfv4(*(const ushort4*)(r2 + 128));
        float4 k3 = bfv4(*(const ushort4*)r3), v3 = bfv4(*(const ushort4*)(r3 + 128));
        float p0 = q.x*k0.x + q.y*k0.y + q.z*k0.z + q.w*k0.w;
        float p1 = q.x*k1.x + q.y*k1.y + q.z*k1.z + q.w*k1.w;
        float p2 = q.x*k2.x + q.y*k2.y + q.z*k2.z + q.w*k2.w;
        float p3 = q.x*k3.x + q.y*k3.y + q.z*k3.z + q.w*k3.w;
        p0 += __shfl_xor(p0, 1, 4); p1 += __shfl_xor(p1, 1, 4);
        p2 += __shfl_xor(p2, 1, 4); p3 += __shfl_xor(p3, 1, 4);
        p0 += __shfl_xor(p0, 2, 4); p1 += __shfl_xor(p1, 2, 4);
        p2 += __shfl_xor(p2, 2, 4); p3 += __shfl_xor(p3, 2, 4);
        upd4(m0, s0, a0, p0, v0);
        upd4(m1, s1, a1, p1, v1);
        upd4(m2, s2, a2, p2, v2);
        upd4(m3, s3, a3, p3, v3);
    }
    for (; i < end; i++) {
        int e0 = es[i];
        const unsigned short* r0 = KV + (size_t)e0 * 256 + 4 * l;
        float4 k0 = bfv4(*(const ushort4*)r0), v0 = bfv4(*(const ushort4*)(r0 + 128));
        float p0 = q.x*k0.x + q.y*k0.y + q.z*k0.z + q.w*k0.w;
        p0 += __shfl_xor(p0, 1, 4);
        p0 += __shfl_xor(p0, 2, 4);
        upd4(m0, s0, a0, p0, v0);
    }
    float M = fmaxf(fmaxf(m0, m1), fmaxf(m2, m3));
    float4 o = {0,0,0,0};
    if (M != -INFINITY) {
        float w0 = __expf(m0 - M), w1 = __expf(m1 - M);
        float w2 = __expf(m2 - M), w3 = __expf(m3 - M);
        float ssum = s0 * w0 + s1 * w1 + s2 * w2 + s3 * w3;
        float inv = 1.f / (ssum + 1e-16f);
        o.x = (a0.x*w0 + a1.x*w1 + a2.x*w2 + a3.x*w3) * inv;
        o.y = (a0.y*w0 + a1.y*w1 + a2.y*w2 + a3.y*w3) * inv;
        o.z = (a0.z*w0 + a1.z*w1 + a2.z*w2 + a3.z*w3) * inv;
        o.w = (a0.w*w0 + a1.w*w1 + a2.w*w2 + a3.w*w3) * inv;
    }
    *(float4*)(out + (size_t)n * 128 + 4 * l) = o;
}

// ---------------- pred: one block per m-node, Em row in regs ----------------
__global__ __launch_bounds__(64) void pred_kernel(
    const float* __restrict__ Em, const float* __restrict__ Ed,
    const int* __restrict__ eidx,
    const int* __restrict__ rpm, const int* __restrict__ porder,
    float* __restrict__ out)
{
    int m = blockIdx.x;
    int lane = threadIdx.x;
    int beg = rpm[m], end = rpm[m + 1];
    if (beg == end) return;
    float4 a = *(const float4*)(Em + (size_t)m * 256 + 4 * lane);
    int i = beg;
    for (; i + 2 <= end; i += 2) {
        int p0 = porder[i], p1 = porder[i + 1];
        int d0 = eidx[Pc + p0], d1 = eidx[Pc + p1];
        float4 b0 = *(const float4*)(Ed + (size_t)d0 * 256 + 4 * lane);
        float4 b1 = *(const float4*)(Ed + (size_t)d1 * 256 + 4 * lane);
        float s0 = a.x*b0.x + a.y*b0.y + a.z*b0.z + a.w*b0.w;
        float s1 = a.x*b1.x + a.y*b1.y + a.z*b1.z + a.w*b1.w;
        #pragma unroll
        for (int o = 1; o < 64; o <<= 1) { s0 += __shfl_xor(s0, o); s1 += __shfl_xor(s1, o); }
        if (lane == 0) { out[p0] = s0; out[p1] = s1; }
    }
    if (i < end) {
        int p0 = porder[i];
        int d0 = eidx[Pc + p0];
        float4 b0 = *(const float4*)(Ed + (size_t)d0 * 256 + 4 * lane);
        float s0 = a.x*b0.x + a.y*b0.y + a.z*b0.z + a.w*b0.w;
        #pragma unroll
        for (int o = 1; o < 64; o <<= 1) s0 += __shfl_xor(s0, o);
        if (lane == 0) out[p0] = s0;
    }
}

extern "C" void kernel_launch(void* const* d_in, const int* in_sizes, int n_in,
                              void* d_out, int out_size, void* d_ws, size_t ws_size,
                              hipStream_t stream)
{
    const float* x1   = (const float*)d_in[0];
    const float* x2   = (const float*)d_in[1];
    const int*   ei12 = (const int*)d_in[2];
    const int*   ei21 = (const int*)d_in[3];
    const int*   eidx = (const int*)d_in[4];
    const float* Win1 = (const float*)d_in[5];
    const float* bin1 = (const float*)d_in[6];
    const float* Win2 = (const float*)d_in[7];
    const float* bin2 = (const float*)d_in[8];
    const float* Wk   = (const float*)d_in[9];
    const float* bk   = (const float*)d_in[10];
    const float* Wq   = (const float*)d_in[11];
    const float* bq   = (const float*)d_in[12];
    const float* Wv   = (const float*)d_in[13];
    const float* bv   = (const float*)d_in[14];
    const float* Wa   = (const float*)d_in[15];
    const float* ba   = (const float*)d_in[16];
    const float* skip = (const float*)d_in[17];
    const float* arel = (const float*)d_in[18];
    const float* mrel = (const float*)d_in[19];
    const float* prior= (const float*)d_in[20];

    char* ws = (char*)d_ws;
    size_t off = 0;
    auto allocB = [&](size_t bytes) { void* p = ws + off; off += (bytes + 15) & ~15ull; return p; };
    auto allocF = [&](size_t n) { return (float*)allocB(n * 4); };
    auto allocI = [&](size_t n) { return (int*)allocB(n * 4); };
    auto allocS = [&](size_t n) { return (short*)allocB(n * 2); };

    float* h1    = allocF((size_t)N1c * 128);
    float* h2    = allocF((size_t)N2c * 128);
    float* Q1    = allocF((size_t)N1c * 128);
    float* Q2    = allocF((size_t)N2c * 128);
    float* agg1  = allocF((size_t)N1c * 128);
    float* agg2  = allocF((size_t)N2c * 128);
    float* Em    = allocF((size_t)N1c * 256);
    float* Ed    = allocF((size_t)N2c * 256);
    float* bqkv  = allocF(4 * 384);
    short* Wqkvt = allocS(4 * 384 * 128);
    short* Wint1 = allocS(128 * 256);
    short* Wint2 = allocS(128 * 256);
    short* Wat   = allocS(4 * 128 * 128);
    unsigned short* KV1 = (unsigned short*)allocS((size_t)N1c * 256);
    unsigned short* KV2 = (unsigned short*)allocS((size_t)N2c * 256);
    int* rp12  = allocI(N2c + 1);
    int* rp21  = allocI(N1c + 1);
    int* rpm   = allocI(N1c + 1);
    int* es12  = allocI(Ec);
    int* es21  = allocI(Ec);
    int* ps    = allocI(Pc);
    int* cntmat = allocI(3 * NPART * NBLK);
    int* offmat = allocI(3 * NPART * NBLK);
    int2* stg12 = (int2*)allocB((size_t)Ec * 8);
    int2* stg21 = (int2*)allocB((size_t)Ec * 8);
    int2* stgm  = (int2*)allocB((size_t)Pc * 8);

    make_eff_kernel<<<dim3(3, 128, 4), 128, 0, stream>>>(
        Wq, bq, Wk, bk, Wv, bv, arel, mrel, prior, Wqkvt, bqkv);
    wt_prep_kernel<<<dim3(128, 6), 256, 0, stream>>>(Win1, Win2, Wa, Wint1, Wint2, Wat);

    count_bins_kernel<<<dim3(NBLK, 3), 256, 0, stream>>>(ei12, ei21, eidx, cntmat);
    scan_bins_kernel<<<3, 256, 0, stream>>>(cntmat, offmat);
    binwrite_kernel<<<dim3(NBLK, 3), 256, 0, stream>>>(ei12, ei21, eidx, offmat,
                                                       stg12, stg21, stgm);
    build_csr_kernel<<<dim3(NPART, 3), 256, 0, stream>>>(offmat, stg12, stg21, stgm,
                                                         rp12, rp21, rpm, es12, es21, ps);

    const int MB = (N1c + 63) / 64;   // 157
    gemm_mfma<0, 1, 0, 0><<<dim3(MB, 2, 2), 256, 0, stream>>>(
        x1, x2, F_INc, Wint1, Wint2, bin1, bin2, h1, h2, 128,
        nullptr, nullptr,
        N1c, F_INc, nullptr, nullptr, nullptr, nullptr, 0);

    for (int l = 0; l < Lc; l++) {
        const float* A1 = (l == 0) ? h1 : Em;  int ld1 = (l == 0) ? 128 : 256;
        const float* A2 = (l == 0) ? h2 : Ed;
        int lt0 = l * 2 + 0, lt1 = l * 2 + 1;
        gemm_mfma<0, 0, 0, 1><<<dim3(MB, 6, 2), 256, 0, stream>>>(
            A1, A2, ld1,
            Wqkvt + (size_t)lt0 * 49152, Wqkvt + (size_t)lt1 * 49152,
            bqkv + lt0 * 384, bqkv + lt1 * 384,
            Q1, Q2, 128,
            KV1, KV2,
            N1c, 128,
            nullptr, nullptr, nullptr, nullptr, 0);
        attend2_kernel<<<(N1c + N2c) / 2, 64, 0, stream>>>(
            Q1, KV1, Q2, KV2, rp12, es12, rp21, es21, agg1, agg2);
        gemm_mfma<1, 0, 1, 0><<<dim3(MB, 2, 2), 256, 0, stream>>>(
            agg1, agg2, 128,
            Wat + (size_t)lt0 * 16384, Wat + (size_t)lt1 * 16384,
            ba + lt0 * 128, ba + lt1 * 128,
            Em + l * 128, Ed + l * 128, 256,
            nullptr, nullptr,
            N1c, 128,
            skip + lt0, skip + lt1,
            A1, A2, ld1);
    }

    pred_kernel<<<N1c, 64, 0, stream>>>(Em, Ed, eidx, rpm, ps, (float*)d_out);
}

// Round 6
// 361.183 us; speedup vs baseline: 4.7560x; 1.0124x over previous
//
#include <hip/hip_runtime.h>
#include <math.h>

#define N1c 10000
#define N2c 10000
#define F_INc 256
#define Ec 480000
#define Pc 200000
#define HIDc 128
#define Hc 8
#define DHc 16
#define Lc 2
#define NPART 32
#define NPc 313   // ceil(10000/32)
#define NBLK 256  // chunks per edge structure

using short8 = __attribute__((ext_vector_type(8))) short;
using float4v = __attribute__((ext_vector_type(4))) float;

__device__ __forceinline__ float gelu_f(float x) {
    const float k0 = 0.7978845608028654f;
    const float k1 = 0.044715f;
    float x3 = x * x * x;
    float t = tanhf(k0 * (x + k1 * x3));
    return 0.5f * x * (1.0f + t);
}

__device__ __forceinline__ float bf2f(unsigned short x) {
    union { unsigned int u; float f; } c;
    c.u = ((unsigned int)x) << 16;
    return c.f;
}
__device__ __forceinline__ unsigned short f2bf(float f) {
    union { float f; unsigned int u; } c;
    c.f = f;
    unsigned int u = c.u;
    unsigned int r = (u + 0x7FFFu + ((u >> 16) & 1u)) >> 16;
    return (unsigned short)r;
}

// ---------------- combined effective weights -> bf16, [n][k] layout ----------------
__global__ __launch_bounds__(128) void make_eff_kernel(
    const float* __restrict__ Wq, const float* __restrict__ bq,
    const float* __restrict__ Wk, const float* __restrict__ bk,
    const float* __restrict__ Wv, const float* __restrict__ bv,
    const float* __restrict__ arel, const float* __restrict__ mrel,
    const float* __restrict__ prior,
    short* __restrict__ Wqkvt, float* __restrict__ bqkv)
{
    int col = blockIdx.x * 128 + threadIdx.x;   // 0..383
    int c = blockIdx.y;                          // 0..127 (k)
    int lt = blockIdx.z;                         // 0..3
    short* Wout = Wqkvt + (size_t)lt * 384 * 128;
    float* bout = bqkv + lt * 384;
    if (col < 128) {
        Wout[col * 128 + c] = (short)f2bf(Wq[lt * 16384 + c * 128 + col]);
        if (c == 0) bout[col] = bq[lt * 128 + col];
        return;
    }
    int which = (col < 256) ? 0 : 1;
    int he = col - (which ? 256 : 128);
    int h = he >> 4, e = he & 15;
    const float* W = (which == 0 ? Wk : Wv) + lt * 16384;
    const float* b = (which == 0 ? bk : bv) + lt * 128;
    const float* R = (which == 0 ? arel : mrel) + lt * 2048;
    float sc = (which == 0) ? prior[lt * 8 + h] * 0.25f : 1.0f;
    float acc = 0.f;
    #pragma unroll
    for (int d = 0; d < 16; d++)
        acc += W[c * 128 + h * 16 + d] * R[(h * 16 + d) * 16 + e];
    Wout[col * 128 + c] = (short)f2bf(acc * sc);
    if (c == 0) {
        float bacc = 0.f;
        #pragma unroll
        for (int d = 0; d < 16; d++)
            bacc += b[h * 16 + d] * R[(h * 16 + d) * 16 + e];
        bout[col] = bacc * sc;
    }
}

// ---------------- transpose+bf16 Win1/Win2/Wa ----------------
__global__ __launch_bounds__(256) void wt_prep_kernel(
    const float* __restrict__ Win1, const float* __restrict__ Win2,
    const float* __restrict__ Wa,
    short* __restrict__ Wint1, short* __restrict__ Wint2, short* __restrict__ Wat)
{
    int y = blockIdx.y;
    int id = blockIdx.x * 256 + threadIdx.x;
    if (y < 2) {   // Win: [256][128] -> [128][256]
        if (id >= 128 * 256) return;
        int n = id >> 8, k = id & 255;
        const float* W = y ? Win2 : Win1;
        short* O = y ? Wint2 : Wint1;
        O[n * 256 + k] = (short)f2bf(W[k * 128 + n]);
    } else {       // Wa[lt]: [128][128] -> transposed
        if (id >= 128 * 128) return;
        int lt = y - 2;
        int n = id >> 7, k = id & 127;
        Wat[lt * 16384 + n * 128 + k] = (short)f2bf(Wa[lt * 16384 + k * 128 + n]);
    }
}

// ---------------- CSR build: two-level binned sort ----------------
__global__ __launch_bounds__(256) void count_bins_kernel(
    const int* __restrict__ ei12, const int* __restrict__ ei21, const int* __restrict__ eidx,
    int* __restrict__ cntmat)   // [z][part][blk]
{
    int blk = blockIdx.x, z = blockIdx.y, t = threadIdx.x;
    const int* key; int E;
    if (z == 0)      { key = ei12 + Ec; E = Ec; }
    else if (z == 1) { key = ei21 + Ec; E = Ec; }
    else             { key = eidx;      E = Pc; }
    int chunk = (E + NBLK - 1) / NBLK;
    int start = blk * chunk;
    int stop = min(start + chunk, E);
    __shared__ int cnt[NPART];
    if (t < NPART) cnt[t] = 0;
    __syncthreads();
    for (int e = start + t; e < stop; e += 256)
        atomicAdd(&cnt[key[e] / NPc], 1);
    __syncthreads();
    if (t < NPART) cntmat[z * (NPART * NBLK) + t * NBLK + blk] = cnt[t];
}

__global__ __launch_bounds__(256) void scan_bins_kernel(
    const int* __restrict__ cntmat, int* __restrict__ offmat)
{
    int z = blockIdx.x, t = threadIdx.x;
    const int* c = cntmat + z * (NPART * NBLK);
    int* o = offmat + z * (NPART * NBLK);
    int loc[32];
    int base = t * 32;
    int s = 0;
    #pragma unroll
    for (int j = 0; j < 32; j++) { loc[j] = s; s += c[base + j]; }
    __shared__ int ws[256];
    ws[t] = s;
    __syncthreads();
    for (int off = 1; off < 256; off <<= 1) {
        int v = (t >= off) ? ws[t - off] : 0;
        __syncthreads();
        ws[t] += v;
        __syncthreads();
    }
    int excl = t ? ws[t - 1] : 0;
    #pragma unroll
    for (int j = 0; j < 32; j++) o[base + j] = excl + loc[j];
}

__global__ __launch_bounds__(256) void binwrite_kernel(
    const int* __restrict__ ei12, const int* __restrict__ ei21, const int* __restrict__ eidx,
    const int* __restrict__ offmat,
    int2* __restrict__ stg12, int2* __restrict__ stg21, int2* __restrict__ stgm)
{
    int blk = blockIdx.x, z = blockIdx.y, t = threadIdx.x;
    const int* key; const int* pay; int E; int2* stg;
    if (z == 0)      { key = ei12 + Ec; pay = ei12; E = Ec; stg = stg12; }
    else if (z == 1) { key = ei21 + Ec; pay = ei21; E = Ec; stg = stg21; }
    else             { key = eidx;      pay = nullptr; E = Pc; stg = stgm; }
    int chunk = (E + NBLK - 1) / NBLK;
    int start = blk * chunk;
    int stop = min(start + chunk, E);
    const int* om = offmat + z * (NPART * NBLK);
    __shared__ int fill[NPART];
    __shared__ int obase[NPART];
    if (t < NPART) { fill[t] = 0; obase[t] = om[t * NBLK + blk]; }
    __syncthreads();
    for (int e = start + t; e < stop; e += 256) {
        int k = key[e];
        int p = k / NPc;
        int r = atomicAdd(&fill[p], 1);
        stg[obase[p] + r] = make_int2(k, (z == 2) ? e : pay[e]);
    }
}

__global__ __launch_bounds__(256) void build_csr_kernel(
    const int* __restrict__ offmat,
    const int2* __restrict__ stg12, const int2* __restrict__ stg21, const int2* __restrict__ stgm,
    int* __restrict__ rp12, int* __restrict__ rp21, int* __restrict__ rpm,
    int* __restrict__ es12, int* __restrict__ es21, int* __restrict__ ps)
{
    int p = blockIdx.x, z = blockIdx.y, t = threadIdx.x;
    const int2* stg; int* rowptr; int* out; int E;
    if (z == 0)      { stg = stg12; rowptr = rp12; out = es12; E = Ec; }
    else if (z == 1) { stg = stg21; rowptr = rp21; out = es21; E = Ec; }
    else             { stg = stgm;  rowptr = rpm;  out = ps;   E = Pc; }
    const int* om = offmat + z * (NPART * NBLK);
    int base = om[p * NBLK];
    int next = (p == NPART - 1) ? E : om[(p + 1) * NBLK];
    int cntP = next - base;
    int lo = p * NPc;
    int hi = min(lo + NPc, 10000);

    __shared__ int hist[512];
    __shared__ int fill[NPc];
    hist[t] = 0; hist[t + 256] = 0;
    __syncthreads();
    for (int i = t; i < cntP; i += 256)
        atomicAdd(&hist[stg[base + i].x - lo], 1);
    __syncthreads();
    for (int off = 1; off < 512; off <<= 1) {
        int i0 = t, i1 = t + 256;
        int v0 = (i0 >= off) ? hist[i0 - off] : 0;
        int v1 = (i1 >= off) ? hist[i1 - off] : 0;
        __syncthreads();
        hist[i0] += v0; hist[i1] += v1;
        __syncthreads();
    }
    for (int i = t; i < NPc; i += 256) {
        int excl = i ? hist[i - 1] : 0;
        fill[i] = excl;
        if (lo + i < hi) rowptr[lo + i] = base + excl;
    }
    if (p == NPART - 1 && t == 0) rowptr[10000] = E;
    __syncthreads();
    for (int i = t; i < cntP; i += 256) {
        int2 pr = stg[base + i];
        int r = atomicAdd(&fill[pr.x - lo], 1);
        out[base + r] = pr.y;
    }
}

// ---------------- bf16 MFMA GEMM: 64x64 tile, 4 waves, 16x16x32 ----------------
template<int A_GELU, int OUT_RELU, int SKIP, int PACKQKV>
__global__ __launch_bounds__(256) void gemm_mfma(
    const float* __restrict__ A0, const float* __restrict__ A1, int ldA,
    const short* __restrict__ Wt0, const short* __restrict__ Wt1,
    const float* __restrict__ b0, const float* __restrict__ b1,
    float* __restrict__ C0, float* __restrict__ C1, int ldC,
    unsigned short* __restrict__ KV0, unsigned short* __restrict__ KV1,
    int M, int K,
    const float* __restrict__ sk0, const float* __restrict__ sk1,
    const float* __restrict__ H0, const float* __restrict__ H1, int ldH)
{
    int z = blockIdx.z;
    const float* A = z ? A1 : A0;
    const short* Wt = z ? Wt1 : Wt0;
    const float* bias = z ? b1 : b0;
    float* C = z ? C1 : C0;
    unsigned short* KVo = z ? KV1 : KV0;
    const float* skipv = z ? sk1 : sk0;
    const float* Hold = z ? H1 : H0;

    __shared__ short Alds[64 * 40];
    __shared__ short Blds[64 * 40];

    int tid = threadIdx.x;
    int w = tid >> 6;
    int l = tid & 63;
    int mBase = blockIdx.x * 64;
    int nBase = blockIdx.y * 64;

    int srow = tid >> 2;
    int koct = tid & 3;

    float4v acc[4];
    #pragma unroll
    for (int i = 0; i < 4; i++) acc[i] = (float4v){0.f, 0.f, 0.f, 0.f};

    int arow = mBase + srow;
    const float* Aptr = A + (size_t)arow * ldA + koct * 8;
    const short* Wptr = Wt + (size_t)(nBase + srow) * K + koct * 8;

    int fl = l & 15;
    int fo = (l >> 4) * 8;

    for (int k0 = 0; k0 < K; k0 += 32) {
        float av[8];
        if (arow < M) {
            const float4* p = (const float4*)(Aptr + k0);
            float4 f0 = p[0], f1 = p[1];
            av[0] = f0.x; av[1] = f0.y; av[2] = f0.z; av[3] = f0.w;
            av[4] = f1.x; av[5] = f1.y; av[6] = f1.z; av[7] = f1.w;
        } else {
            #pragma unroll
            for (int i = 0; i < 8; i++) av[i] = 0.f;
        }
        if (A_GELU) {
            #pragma unroll
            for (int i = 0; i < 8; i++) av[i] = gelu_f(av[i]);
        }
        unsigned int pk[4];
        #pragma unroll
        for (int i = 0; i < 4; i++)
            pk[i] = (unsigned int)f2bf(av[2 * i]) | ((unsigned int)f2bf(av[2 * i + 1]) << 16);
        *(uint4*)&Alds[srow * 40 + koct * 8] = make_uint4(pk[0], pk[1], pk[2], pk[3]);
        *(uint4*)&Blds[srow * 40 + koct * 8] = *(const uint4*)(Wptr + k0);
        __syncthreads();

        short8 bfr = *(const short8*)&Blds[(w * 16 + fl) * 40 + fo];
        #pragma unroll
        for (int msub = 0; msub < 4; msub++) {
            short8 afr = *(const short8*)&Alds[(msub * 16 + fl) * 40 + fo];
            acc[msub] = __builtin_amdgcn_mfma_f32_16x16x32_bf16(afr, bfr, acc[msub], 0, 0, 0);
        }
        __syncthreads();
    }

    float sig = 0.f;
    if (SKIP) sig = 1.f / (1.f + __expf(-skipv[0]));
    int col = nBase + w * 16 + fl;
    float bcol = bias[col];
    int rbase = mBase + ((l >> 4) * 4);
    #pragma unroll
    for (int msub = 0; msub < 4; msub++) {
        #pragma unroll
        for (int r = 0; r < 4; r++) {
            int row = rbase + msub * 16 + r;
            if (row >= M) continue;
            float v = acc[msub][r] + bcol;
            if (OUT_RELU) v = fmaxf(v, 0.f);
            if (SKIP) v = sig * v + (1.f - sig) * Hold[(size_t)row * ldH + col];
            if (PACKQKV) {
                if (col < 128) C[(size_t)row * ldC + col] = v;
                else KVo[(size_t)row * 256 + (col - 128)] = f2bf(v);
            } else {
                C[(size_t)row * ldC + col] = v;
            }
        }
    }
}

// ---------------- merged attend: 8 nodes/block (256 thr), direct-exp softmax ----------------
// logits = q.k*prior/4 are O(1..20): exp() safe in fp32 without max subtraction
// (softmax is shift-invariant; empty rows give 0/(0+1e-16)=0 like the reference).
__device__ __forceinline__ float4 bfv4(ushort4 u) {
    return make_float4(bf2f(u.x), bf2f(u.y), bf2f(u.z), bf2f(u.w));
}

__global__ __launch_bounds__(256) void attend2_kernel(
    const float* __restrict__ Q1, const unsigned short* __restrict__ KV1,
    const float* __restrict__ Q2, const unsigned short* __restrict__ KV2,
    const int* __restrict__ rp12, const int* __restrict__ es12,
    const int* __restrict__ rp21, const int* __restrict__ es21,
    float* __restrict__ agg1, float* __restrict__ agg2)
{
    int g = blockIdx.x * 8 + (threadIdx.x >> 5);   // global node slot 0..19999
    int l = threadIdx.x & 31;
    const float* Q; const unsigned short* KV; const int* rp; const int* es; float* out; int n;
    if (g < N2c) { n = g;       Q = Q2; KV = KV1; rp = rp12; es = es12; out = agg2; }
    else         { n = g - N2c; Q = Q1; KV = KV2; rp = rp21; es = es21; out = agg1; }

    float4 q = *(const float4*)(Q + (size_t)n * 128 + 4 * l);
    int beg = rp[n], end = rp[n + 1];
    float s0 = 0.f, s1 = 0.f, s2 = 0.f, s3 = 0.f;
    float4 a0 = {0,0,0,0}, a1 = {0,0,0,0}, a2 = {0,0,0,0}, a3 = {0,0,0,0};
    int i = beg;
    for (; i + 4 <= end; i += 4) {
        int e0 = es[i], e1 = es[i+1], e2 = es[i+2], e3 = es[i+3];
        const unsigned short* r0 = KV + (size_t)e0 * 256 + 4 * l;
        const unsigned short* r1 = KV + (size_t)e1 * 256 + 4 * l;
        const unsigned short* r2 = KV + (size_t)e2 * 256 + 4 * l;
        const unsigned short* r3 = KV + (size_t)e3 * 256 + 4 * l;
        float4 k0 = bfv4(*(const ushort4*)r0), v0 = bfv4(*(const ushort4*)(r0 + 128));
        float4 k1 = bfv4(*(const ushort4*)r1), v1 = bfv4(*(const ushort4*)(r1 + 128));
        float4 k2 = bfv4(*(const ushort4*)r2), v2 = bfv4(*(const ushort4*)(r2 + 128));
        float4 k3 = bfv4(*(const ushort4*)r3), v3 = bfv4(*(const ushort4*)(r3 + 128));
        float p0 = q.x*k0.x + q.y*k0.y + q.z*k0.z + q.w*k0.w;
        float p1 = q.x*k1.x + q.y*k1.y + q.z*k1.z + q.w*k1.w;
        float p2 = q.x*k2.x + q.y*k2.y + q.z*k2.z + q.w*k2.w;
        float p3 = q.x*k3.x + q.y*k3.y + q.z*k3.z + q.w*k3.w;
        p0 += __shfl_xor(p0, 1, 4); p1 += __shfl_xor(p1, 1, 4);
        p2 += __shfl_xor(p2, 1, 4); p3 += __shfl_xor(p3, 1, 4);
        p0 += __shfl_xor(p0, 2, 4); p1 += __shfl_xor(p1, 2, 4);
        p2 += __shfl_xor(p2, 2, 4); p3 += __shfl_xor(p3, 2, 4);
        float x0 = __expf(p0), x1 = __expf(p1), x2 = __expf(p2), x3 = __expf(p3);
        s0 += x0; s1 += x1; s2 += x2; s3 += x3;
        a0.x += x0*v0.x; a0.y += x0*v0.y; a0.z += x0*v0.z; a0.w += x0*v0.w;
        a1.x += x1*v1.x; a1.y += x1*v1.y; a1.z += x1*v1.z; a1.w += x1*v1.w;
        a2.x += x2*v2.x; a2.y += x2*v2.y; a2.z += x2*v2.z; a2.w += x2*v2.w;
        a3.x += x3*v3.x; a3.y += x3*v3.y; a3.z += x3*v3.z; a3.w += x3*v3.w;
    }
    for (; i < end; i++) {
        int e0 = es[i];
        const unsigned short* r0 = KV + (size_t)e0 * 256 + 4 * l;
        float4 k0 = bfv4(*(const ushort4*)r0), v0 = bfv4(*(const ushort4*)(r0 + 128));
        float p0 = q.x*k0.x + q.y*k0.y + q.z*k0.z + q.w*k0.w;
        p0 += __shfl_xor(p0, 1, 4);
        p0 += __shfl_xor(p0, 2, 4);
        float x0 = __expf(p0);
        s0 += x0;
        a0.x += x0*v0.x; a0.y += x0*v0.y; a0.z += x0*v0.z; a0.w += x0*v0.w;
    }
    float ssum = (s0 + s1) + (s2 + s3);
    float inv = 1.f / (ssum + 1e-16f);
    float4 o;
    o.x = ((a0.x + a1.x) + (a2.x + a3.x)) * inv;
    o.y = ((a0.y + a1.y) + (a2.y + a3.y)) * inv;
    o.z = ((a0.z + a1.z) + (a2.z + a3.z)) * inv;
    o.w = ((a0.w + a1.w) + (a2.w + a3.w)) * inv;
    *(float4*)(out + (size_t)n * 128 + 4 * l) = o;
}

// ---------------- pred: 4 m-nodes/block (256 thr), Em row in regs ----------------
__global__ __launch_bounds__(256) void pred_kernel(
    const float* __restrict__ Em, const float* __restrict__ Ed,
    const int* __restrict__ eidx,
    const int* __restrict__ rpm, const int* __restrict__ porder,
    float* __restrict__ out)
{
    int m = blockIdx.x * 4 + (threadIdx.x >> 6);
    int lane = threadIdx.x & 63;
    int beg = rpm[m], end = rpm[m + 1];
    if (beg == end) return;
    float4 a = *(const float4*)(Em + (size_t)m * 256 + 4 * lane);
    int i = beg;
    for (; i + 2 <= end; i += 2) {
        int p0 = porder[i], p1 = porder[i + 1];
        int d0 = eidx[Pc + p0], d1 = eidx[Pc + p1];
        float4 b0 = *(const float4*)(Ed + (size_t)d0 * 256 + 4 * lane);
        float4 b1 = *(const float4*)(Ed + (size_t)d1 * 256 + 4 * lane);
        float s0 = a.x*b0.x + a.y*b0.y + a.z*b0.z + a.w*b0.w;
        float s1 = a.x*b1.x + a.y*b1.y + a.z*b1.z + a.w*b1.w;
        #pragma unroll
        for (int o = 1; o < 64; o <<= 1) { s0 += __shfl_xor(s0, o); s1 += __shfl_xor(s1, o); }
        if (lane == 0) { out[p0] = s0; out[p1] = s1; }
    }
    if (i < end) {
        int p0 = porder[i];
        int d0 = eidx[Pc + p0];
        float4 b0 = *(const float4*)(Ed + (size_t)d0 * 256 + 4 * lane);
        float s0 = a.x*b0.x + a.y*b0.y + a.z*b0.z + a.w*b0.w;
        #pragma unroll
        for (int o = 1; o < 64; o <<= 1) s0 += __shfl_xor(s0, o);
        if (lane == 0) out[p0] = s0;
    }
}

extern "C" void kernel_launch(void* const* d_in, const int* in_sizes, int n_in,
                              void* d_out, int out_size, void* d_ws, size_t ws_size,
                              hipStream_t stream)
{
    const float* x1   = (const float*)d_in[0];
    const float* x2   = (const float*)d_in[1];
    const int*   ei12 = (const int*)d_in[2];
    const int*   ei21 = (const int*)d_in[3];
    const int*   eidx = (const int*)d_in[4];
    const float* Win1 = (const float*)d_in[5];
    const float* bin1 = (const float*)d_in[6];
    const float* Win2 = (const float*)d_in[7];
    const float* bin2 = (const float*)d_in[8];
    const float* Wk   = (const float*)d_in[9];
    const float* bk   = (const float*)d_in[10];
    const float* Wq   = (const float*)d_in[11];
    const float* bq   = (const float*)d_in[12];
    const float* Wv   = (const float*)d_in[13];
    const float* bv   = (const float*)d_in[14];
    const float* Wa   = (const float*)d_in[15];
    const float* ba   = (const float*)d_in[16];
    const float* skip = (const float*)d_in[17];
    const float* arel = (const float*)d_in[18];
    const float* mrel = (const float*)d_in[19];
    const float* prior= (const float*)d_in[20];

    char* ws = (char*)d_ws;
    size_t off = 0;
    auto allocB = [&](size_t bytes) { void* p = ws + off; off += (bytes + 15) & ~15ull; return p; };
    auto allocF = [&](size_t n) { return (float*)allocB(n * 4); };
    auto allocI = [&](size_t n) { return (int*)allocB(n * 4); };
    auto allocS = [&](size_t n) { return (short*)allocB(n * 2); };

    float* h1    = allocF((size_t)N1c * 128);
    float* h2    = allocF((size_t)N2c * 128);
    float* Q1    = allocF((size_t)N1c * 128);
    float* Q2    = allocF((size_t)N2c * 128);
    float* agg1  = allocF((size_t)N1c * 128);
    float* agg2  = allocF((size_t)N2c * 128);
    float* Em    = allocF((size_t)N1c * 256);
    float* Ed    = allocF((size_t)N2c * 256);
    float* bqkv  = allocF(4 * 384);
    short* Wqkvt = allocS(4 * 384 * 128);
    short* Wint1 = allocS(128 * 256);
    short* Wint2 = allocS(128 * 256);
    short* Wat   = allocS(4 * 128 * 128);
    unsigned short* KV1 = (unsigned short*)allocS((size_t)N1c * 256);
    unsigned short* KV2 = (unsigned short*)allocS((size_t)N2c * 256);
    int* rp12  = allocI(N2c + 1);
    int* rp21  = allocI(N1c + 1);
    int* rpm   = allocI(N1c + 1);
    int* es12  = allocI(Ec);
    int* es21  = allocI(Ec);
    int* ps    = allocI(Pc);
    int* cntmat = allocI(3 * NPART * NBLK);
    int* offmat = allocI(3 * NPART * NBLK);
    int2* stg12 = (int2*)allocB((size_t)Ec * 8);
    int2* stg21 = (int2*)allocB((size_t)Ec * 8);
    int2* stgm  = (int2*)allocB((size_t)Pc * 8);

    make_eff_kernel<<<dim3(3, 128, 4), 128, 0, stream>>>(
        Wq, bq, Wk, bk, Wv, bv, arel, mrel, prior, Wqkvt, bqkv);
    wt_prep_kernel<<<dim3(128, 6), 256, 0, stream>>>(Win1, Win2, Wa, Wint1, Wint2, Wat);

    count_bins_kernel<<<dim3(NBLK, 3), 256, 0, stream>>>(ei12, ei21, eidx, cntmat);
    scan_bins_kernel<<<3, 256, 0, stream>>>(cntmat, offmat);
    binwrite_kernel<<<dim3(NBLK, 3), 256, 0, stream>>>(ei12, ei21, eidx, offmat,
                                                       stg12, stg21, stgm);
    build_csr_kernel<<<dim3(NPART, 3), 256, 0, stream>>>(offmat, stg12, stg21, stgm,
                                                         rp12, rp21, rpm, es12, es21, ps);

    const int MB = (N1c + 63) / 64;   // 157
    gemm_mfma<0, 1, 0, 0><<<dim3(MB, 2, 2), 256, 0, stream>>>(
        x1, x2, F_INc, Wint1, Wint2, bin1, bin2, h1, h2, 128,
        nullptr, nullptr,
        N1c, F_INc, nullptr, nullptr, nullptr, nullptr, 0);

    for (int l = 0; l < Lc; l++) {
        const float* A1 = (l == 0) ? h1 : Em;  int ld1 = (l == 0) ? 128 : 256;
        const float* A2 = (l == 0) ? h2 : Ed;
        int lt0 = l * 2 + 0, lt1 = l * 2 + 1;
        gemm_mfma<0, 0, 0, 1><<<dim3(MB, 6, 2), 256, 0, stream>>>(
            A1, A2, ld1,
            Wqkvt + (size_t)lt0 * 49152, Wqkvt + (size_t)lt1 * 49152,
            bqkv + lt0 * 384, bqkv + lt1 * 384,
            Q1, Q2, 128,
            KV1, KV2,
            N1c, 128,
            nullptr, nullptr, nullptr, nullptr, 0);
        attend2_kernel<<<(N1c + N2c) / 8, 256, 0, stream>>>(
            Q1, KV1, Q2, KV2, rp12, es12, rp21, es21, agg1, agg2);
        gemm_mfma<1, 0, 1, 0><<<dim3(MB, 2, 2), 256, 0, stream>>>(
            agg1, agg2, 128,
            Wat + (size_t)lt0 * 16384, Wat + (size_t)lt1 * 16384,
            ba + lt0 * 128, ba + lt1 * 128,
            Em + l * 128, Ed + l * 128, 256,
            nullptr, nullptr,
            N1c, 128,
            skip + lt0, skip + lt1,
            A1, A2, ld1);
    }

    pred_kernel<<<N1c / 4, 256, 0, stream>>>(Em, Ed, eidx, rpm, ps, (float*)d_out);
}